// Round 8
// baseline (53.735 us; speedup 1.0000x reference)
//
#include <hip/hip_runtime.h>
#include <cstdint>
#include <cstddef>

typedef short short8 __attribute__((ext_vector_type(8)));
typedef float f32x4 __attribute__((ext_vector_type(4)));

#define BB 16
#define SS 512
#define TT 64
#define LL 64
#define UU 128
#define NV 40000

// ws layout (bytes)
#define WT_OFF    0u                        // W_trans frags: 32KB
#define WHT_OFF   (WT_OFF + 32768u)         // W_ht frags: 64KB
#define WREL_OFF  (WHT_OFF + 65536u)        // W_rel frags: 32KB
#define TE_OFF    (WREL_OFF + 32768u)       // te table bf16: 10.24MB
#define A_OFF     (TE_OFF  + 40000u*128u*2u)  // A = te@Wht_top + b_ht (f32): 20.48MB
#define B2_OFF    (A_OFF   + 40000u*128u*4u)  // B = te@Wht_bot (f32)
#define R_OFF     (B2_OFF  + 40000u*128u*4u)  // R = te@Wrel + b_rel (f32)

__device__ __forceinline__ unsigned short f2bf(float x) {  // rtne f32->bf16
  unsigned u = __float_as_uint(x);
  unsigned r = ((u >> 16) & 1u) + 0x7FFFu;
  return (unsigned short)((u + r) >> 16);
}
__device__ __forceinline__ float ftanh(float x) {  // 1 - 2/(e^2x+1)
  float e = __expf(2.0f * x);
  return 1.0f - __fdividef(2.0f, e + 1.0f);
}
__device__ __forceinline__ unsigned cvtpk(float a, float b) {
  unsigned r;
  asm("v_cvt_pk_bf16_f32 %0, %1, %2" : "=v"(r) : "v"(a), "v"(b));
  return r;
}
template<int CTRL>
__device__ __forceinline__ float dpp_mov(float x) {
  return __int_as_float(__builtin_amdgcn_update_dpp(
      0, __float_as_int(x), CTRL, 0xF, 0xF, true));
}
__device__ __forceinline__ float row16_sum(float x) {  // verified r1-r7
  x += dpp_mov<0xB1>(x);
  x += dpp_mov<0x4E>(x);
  x += dpp_mov<0x141>(x);
  x += dpp_mov<0x140>(x);
  return x;
}
__device__ __forceinline__ float full64_sum(float x) {
  x = row16_sum(x);
  x += __shfl_xor(x, 16, 64);
  x += __shfl_xor(x, 32, 64);
  return x;
}
__device__ __forceinline__ float full64_max(float x) {
  x = fmaxf(x, dpp_mov<0xB1>(x));
  x = fmaxf(x, dpp_mov<0x4E>(x));
  x = fmaxf(x, dpp_mov<0x141>(x));
  x = fmaxf(x, dpp_mov<0x140>(x));
  x = fmaxf(x, __shfl_xor(x, 16, 64));
  x = fmaxf(x, __shfl_xor(x, 32, 64));
  return x;
}

// ---- prep A: pack W into bf16 fragments (hi only). 32 blocks. -------------
__global__ void prep_kernel(const float* __restrict__ Wt,
                            const float* __restrict__ Wht,
                            const float* __restrict__ Wrel,
                            unsigned char* __restrict__ ws) {
  int slot = blockIdx.x * 256 + threadIdx.x;      // 8192 slots
  const float* W;
  unsigned char* base;
  if (slot < 2048)      { W = Wt;   base = ws + WT_OFF; }
  else if (slot < 6144) { W = Wht;  base = ws + WHT_OFF;  slot -= 2048; }
  else                  { W = Wrel; base = ws + WREL_OFF; slot -= 6144; }
  int lane = slot & 63, pair = slot >> 6;
  int n  = (pair & 7) * 16 + (lane & 15);
  int k0 = (pair >> 3) * 32 + (lane >> 4) * 8;
  short8 hv;
  #pragma unroll
  for (int j = 0; j < 8; ++j)
    hv[j] = (short)f2bf(W[(size_t)(k0 + j) * UU + n]);
  *reinterpret_cast<short8*>(base + (size_t)pair * 1024 + lane * 16) = hv;
}

// ---- prep B: per-vocab te + A/B/R tables ----------------------------------
// te[v] = tanh(emb[v]@W_trans + b_trans)           (bf16, for weighted-sum)
// A[v]  = te[v]@W_ht[0:128]   + b_ht               (f32, head part, bias folded)
// B[v]  = te[v]@W_ht[128:256]                      (f32, tail part)
// R[v]  = te[v]@W_rel         + b_rel              (f32)
// Exact linear split of the old in-block GEMM2 -> numerics preserved.
// 209 blocks x 1024 threads, 192 consecutive vocab rows each (clamped).
__launch_bounds__(1024, 4)
__global__ void prep_all(const float* __restrict__ emb_f32,
                         const float* __restrict__ b_trans,
                         const float* __restrict__ b_ht,
                         const float* __restrict__ b_rel,
                         const unsigned char* __restrict__ wsr,
                         unsigned short* __restrict__ te_g,
                         float* __restrict__ A_g,
                         float* __restrict__ B_g,
                         float* __restrict__ R_g) {
  __shared__ unsigned short TEB[192 * 128];
  const int tid  = threadIdx.x;
  const int base = blockIdx.x * 192;
  const int w    = tid >> 6;
  const int lane = tid & 63;
  const int li   = lane & 15;
  const int lg   = lane >> 4;
  const int nt   = w & 7;
  const int rh   = w >> 3;

  // stage 192 consecutive emb rows (f32 -> bf16, swizzled) — coalesced
  float4 xv[3], yv[3];
  #pragma unroll
  for (int j = 0; j < 3; ++j) {
    int o = tid + j * 1024, row = o >> 4, pc = o & 15;
    int grow = base + row; if (grow > NV - 1) grow = NV - 1;
    int clog = pc ^ (row & 15);
    const float* fb = emb_f32 + (size_t)grow * UU + clog * 8;
    xv[j] = *reinterpret_cast<const float4*>(fb);
    yv[j] = *reinterpret_cast<const float4*>(fb + 4);
  }
  const unsigned char* wtb  = wsr + WT_OFF;
  const unsigned char* whtb = wsr + WHT_OFF;
  const unsigned char* wrlb = wsr + WREL_OFF;
  short8 B1h[4];
  #pragma unroll
  for (int kt = 0; kt < 4; ++kt)
    B1h[kt] = *reinterpret_cast<const short8*>(
        wtb + (size_t)(kt * 8 + nt) * 1024 + lane * 16);
  #pragma unroll
  for (int j = 0; j < 3; ++j) {
    int o = tid + j * 1024;
    uint4 pk = { cvtpk(xv[j].x, xv[j].y), cvtpk(xv[j].z, xv[j].w),
                 cvtpk(yv[j].x, yv[j].y), cvtpk(yv[j].z, yv[j].w) };
    *reinterpret_cast<uint4*>(&TEB[o * 8]) = pk;
  }
  const float4 btr4 = *reinterpret_cast<const float4*>(b_trans + nt * 16 + lg * 4);
  __syncthreads();

  // GEMM1: 6 row-tiles x 4 kt per wave (verbatim, verified r0-r7)
  f32x4 acc[6];
  #pragma unroll
  for (int q = 0; q < 6; ++q) acc[q] = f32x4{0.f, 0.f, 0.f, 0.f};
  #pragma unroll
  for (int kt = 0; kt < 4; ++kt) {
    #pragma unroll
    for (int q = 0; q < 6; ++q) {
      const short8 b = *reinterpret_cast<const short8*>(
          &TEB[((rh * 6 + q) * 16 + li) * 128 + (((kt * 4 + lg) ^ li) << 3)]);
      acc[q] = __builtin_amdgcn_mfma_f32_16x16x32_bf16(B1h[kt], b, acc[q], 0, 0, 0);
    }
  }
  __syncthreads();  // all emb reads done before te overwrite

  // epilogue: te -> TEB (swizzled, input to next GEMMs) AND te_g (global)
  const int cc8 = nt * 2 + (lg >> 1);
  const int hb8 = (lg & 1) << 3;
  #pragma unroll
  for (int q = 0; q < 6; ++q) {
    int row  = (rh * 6 + q) * 16 + li;
    int grow = base + row; if (grow > NV - 1) grow = NV - 1;  // dup write, same value
    float v0 = ftanh(acc[q][0] + btr4.x);
    float v1 = ftanh(acc[q][1] + btr4.y);
    float v2 = ftanh(acc[q][2] + btr4.z);
    float v3 = ftanh(acc[q][3] + btr4.w);
    uint2 pk = { cvtpk(v0, v1), cvtpk(v2, v3) };
    *reinterpret_cast<uint2*>(
        reinterpret_cast<char*>(TEB) + row * 256 + (((cc8 ^ li) << 4) | hb8)) = pk;
    *reinterpret_cast<uint2*>(te_g + (size_t)grow * UU + nt * 16 + lg * 4) = pk;
  }
  __syncthreads();  // te in TEB ready

  // three K=128 GEMMs off te: A (Wht kt0-3, +b_ht), B (Wht kt4-7), R (Wrel, +b_rel)
  const float4 bht4 = *reinterpret_cast<const float4*>(b_ht + nt * 16 + lg * 4);
  const float4 brl4 = *reinterpret_cast<const float4*>(b_rel + nt * 16 + lg * 4);
  #pragma unroll
  for (int pass = 0; pass < 3; ++pass) {
    const unsigned char* wb = (pass == 2) ? wrlb : whtb;
    const int ktoff = (pass == 1) ? 4 : 0;
    f32x4 a2[6];
    #pragma unroll
    for (int q = 0; q < 6; ++q) a2[q] = f32x4{0.f, 0.f, 0.f, 0.f};
    #pragma unroll
    for (int kt = 0; kt < 4; ++kt) {
      const short8 Wf = *reinterpret_cast<const short8*>(
          wb + (size_t)((kt + ktoff) * 8 + nt) * 1024 + lane * 16);
      #pragma unroll
      for (int q = 0; q < 6; ++q) {
        const short8 b = *reinterpret_cast<const short8*>(
            &TEB[((rh * 6 + q) * 16 + li) * 128 + (((kt * 4 + lg) ^ li) << 3)]);
        a2[q] = __builtin_amdgcn_mfma_f32_16x16x32_bf16(Wf, b, a2[q], 0, 0, 0);
      }
    }
    float* out_g = (pass == 0) ? A_g : (pass == 1) ? B_g : R_g;
    float4 bias = (pass == 0) ? bht4
               : (pass == 2) ? brl4 : float4{0.f, 0.f, 0.f, 0.f};
    #pragma unroll
    for (int q = 0; q < 6; ++q) {
      int row  = (rh * 6 + q) * 16 + li;
      int grow = base + row; if (grow > NV - 1) grow = NV - 1;
      float4 v = { a2[q][0] + bias.x, a2[q][1] + bias.y,
                   a2[q][2] + bias.z, a2[q][3] + bias.w };
      *reinterpret_cast<float4*>(out_g + (size_t)grow * UU + nt * 16 + lg * 4) = v;
    }
  }
}

// ---- fused per-(b,t) kernel: 1024 blocks x 1024 threads — NO MFMA ---------
// e_weight[l] = sum_u tanh(A[h_l][u]+B[t_l][u]) * R[r_l][u]: 16 threads per
// triple, 8 dims each, DPP row16 reduce.  TEB stages only the 128 head/tail
// te rows (linear layout, conflict-free).  Barriers: 2.
__launch_bounds__(1024, 8)
__global__ void fused_bt(const int* __restrict__ triples,
                         const unsigned short* __restrict__ te_g,
                         const float* __restrict__ A_g,
                         const float* __restrict__ B_g,
                         const float* __restrict__ R_g,
                         const int* __restrict__ sent_triples,
                         float* __restrict__ out) {
  __shared__ unsigned short TEB[128 * 128];    // 32KB: head|tail te rows
  __shared__ float EWt[64];
  __shared__ float PART[8][256];
  __shared__ int MATCH[512];
  __shared__ int NM;

  const int tid  = threadIdx.x;
  const int bt   = blockIdx.x;
  const int w    = tid >> 6;
  const int lane = tid & 63;
  const int l    = tid >> 4;      // triple 0..63
  const int d8   = tid & 15;      // dim-octet 0..15

  // tokens: 16 threads/group hit the same 3 addresses -> broadcast loads
  const int* tb = triples + (size_t)bt * 192;
  const int th = tb[3 * l], tr = tb[3 * l + 1], tt = tb[3 * l + 2];

  int sidx = -1;
  if (tid < SS) sidx = sent_triples[(size_t)(bt >> 6) * SS + tid];
  if (tid == 0) NM = 0;

  // ---- stage te[head_l] -> TEB row l, te[tail_l] -> TEB row 64+l ---------
  // slot (l, d8): 16 threads read 256B contiguous per row. Linear store.
  short8 svh = *reinterpret_cast<const short8*>(te_g + (size_t)th * UU + d8 * 8);
  short8 svt = *reinterpret_cast<const short8*>(te_g + (size_t)tt * UU + d8 * 8);

  // ---- e_weight partial: 8 dims of tanh(A+B)*R ---------------------------
  const float* Ap = A_g + (size_t)th * UU + d8 * 8;
  const float* Bp = B_g + (size_t)tt * UU + d8 * 8;
  const float* Rp = R_g + (size_t)tr * UU + d8 * 8;
  float4 a0 = *reinterpret_cast<const float4*>(Ap);
  float4 a1 = *reinterpret_cast<const float4*>(Ap + 4);
  float4 b0 = *reinterpret_cast<const float4*>(Bp);
  float4 b1 = *reinterpret_cast<const float4*>(Bp + 4);
  float4 r0 = *reinterpret_cast<const float4*>(Rp);
  float4 r1 = *reinterpret_cast<const float4*>(Rp + 4);

  *reinterpret_cast<short8*>(&TEB[(l * 16 + d8) * 8]) = svh;
  *reinterpret_cast<short8*>(&TEB[((64 + l) * 16 + d8) * 8]) = svt;

  float p = 0.f;
  p = fmaf(ftanh(a0.x + b0.x), r0.x, p);
  p = fmaf(ftanh(a0.y + b0.y), r0.y, p);
  p = fmaf(ftanh(a0.z + b0.z), r0.z, p);
  p = fmaf(ftanh(a0.w + b0.w), r0.w, p);
  p = fmaf(ftanh(a1.x + b1.x), r1.x, p);
  p = fmaf(ftanh(a1.y + b1.y), r1.y, p);
  p = fmaf(ftanh(a1.z + b1.z), r1.z, p);
  p = fmaf(ftanh(a1.w + b1.w), r1.w, p);
  p = row16_sum(p);               // 16-lane groups == d8 groups
  if (d8 == 0) EWt[l] = p;
  __syncthreads();  // (b1) TEB + EWt + NM ready

  // match-find: overlaps softmax/wsum (MATCH/NM read after b2)
  if (sidx == (bt & 63))
    MATCH[atomicAdd(&NM, 1)] = tid;

  // redundant per-wave softmax (verified r5-r7)
  float alpha;
  {
    float e = EWt[lane];
    float mx = full64_max(e);
    float ex = __expf(e - mx);
    float sm = full64_sum(ex);
    alpha = ex / sm;              // lane holds alpha[lane]
  }

  // weighted sum: paired-bf16 b32 reads, 8 l's per thread, conflict-free
  {
    int cp  = tid & 127, lgp = w >> 1;    // wave-uniform l-group
    int c0  = cp << 1;
    int k   = c0 >> 7;                    // 0: head rows 0..63, 1: tail 64..127
    int cc  = c0 & 127;
    float o0 = 0.f, o1 = 0.f;
    #pragma unroll
    for (int j = 0; j < 8; ++j) {
      int lr  = lgp * 8 + j;
      float al = __int_as_float(
          __builtin_amdgcn_readlane(__float_as_int(alpha), lr));
      int row = (k << 6) + lr;
      unsigned u = *reinterpret_cast<const unsigned*>(
          reinterpret_cast<const char*>(TEB) + row * 256 + cc * 2);
      o0 = fmaf(al, __uint_as_float(u << 16), o0);
      o1 = fmaf(al, __uint_as_float(u & 0xFFFF0000u), o1);
    }
    *reinterpret_cast<float2*>(&PART[lgp][c0]) = make_float2(o0, o1);
  }
  __syncthreads();  // (b2) PART + MATCH/NM ready

  // scatter: participating waves fold the 8-way reduce (verified r5-r7)
  {
    const int b  = bt >> 6;
    const int nm = NM;
    if (w < nm) {
      float4 v = {0.f, 0.f, 0.f, 0.f};
      #pragma unroll
      for (int g = 0; g < 8; ++g) {
        float4 pp = reinterpret_cast<const float4*>(&PART[g][0])[lane];
        v.x += pp.x; v.y += pp.y; v.z += pp.z; v.w += pp.w;
      }
      for (int q = w; q < nm; q += 16) {
        int s = MATCH[q];
        reinterpret_cast<float4*>(out + ((size_t)(b * SS + s)) * 256)[lane] = v;
      }
    }
  }
}

extern "C" void kernel_launch(void* const* d_in, const int* in_sizes, int n_in,
                              void* d_out, int out_size, void* d_ws, size_t ws_size,
                              hipStream_t stream) {
  const int*   triples      = (const int*)d_in[1];
  const int*   sent_triples = (const int*)d_in[2];
  const float* emb_table    = (const float*)d_in[3];
  const float* W_trans      = (const float*)d_in[4];
  const float* b_trans      = (const float*)d_in[5];
  const float* W_ht         = (const float*)d_in[6];
  const float* b_ht         = (const float*)d_in[7];
  const float* W_rel        = (const float*)d_in[8];
  const float* b_rel        = (const float*)d_in[9];
  float* out = (float*)d_out;
  unsigned char* ws = (unsigned char*)d_ws;
  unsigned short* te_g = (unsigned short*)(ws + TE_OFF);
  float* A_g = (float*)(ws + A_OFF);
  float* B_g = (float*)(ws + B2_OFF);
  float* R_g = (float*)(ws + R_OFF);

  prep_kernel<<<32, 256, 0, stream>>>(W_trans, W_ht, W_rel, ws);
  prep_all<<<(NV + 191) / 192, 1024, 0, stream>>>(
      emb_table, b_trans, b_ht, b_rel, ws, te_g, A_g, B_g, R_g);
  fused_bt<<<BB * TT, 1024, 0, stream>>>(
      triples, te_g, A_g, B_g, R_g, sent_triples, ws ? out : out);
}

// Round 9
// 47.504 us; speedup vs baseline: 1.1312x; 1.1312x over previous
//
#include <hip/hip_runtime.h>
#include <cstdint>
#include <cstddef>

typedef short short8 __attribute__((ext_vector_type(8)));
typedef float f32x4 __attribute__((ext_vector_type(4)));

#define BB 16
#define SS 512
#define TT 64
#define LL 64
#define UU 128
#define NV 40000

// ws layout (bytes)
#define WT_OFF    0u                          // W_trans frags: 32KB
#define WHT_OFF   (WT_OFF + 32768u)           // W_ht frags: 64KB
#define WREL_OFF  (WHT_OFF + 65536u)          // W_rel frags: 32KB
#define TE_OFF    (WREL_OFF + 32768u)         // te table bf16: 10.24MB
#define R_OFF     (TE_OFF + 40000u*128u*2u)   // R = te@W_rel + b_rel (f32): 20.48MB

__device__ __forceinline__ unsigned short f2bf(float x) {  // rtne f32->bf16
  unsigned u = __float_as_uint(x);
  unsigned r = ((u >> 16) & 1u) + 0x7FFFu;
  return (unsigned short)((u + r) >> 16);
}
__device__ __forceinline__ float ftanh(float x) {  // 1 - 2/(e^2x+1)
  float e = __expf(2.0f * x);
  return 1.0f - __fdividef(2.0f, e + 1.0f);
}
__device__ __forceinline__ unsigned cvtpk(float a, float b) {
  unsigned r;
  asm("v_cvt_pk_bf16_f32 %0, %1, %2" : "=v"(r) : "v"(a), "v"(b));
  return r;
}
template<int CTRL>
__device__ __forceinline__ float dpp_mov(float x) {
  return __int_as_float(__builtin_amdgcn_update_dpp(
      0, __float_as_int(x), CTRL, 0xF, 0xF, true));
}
__device__ __forceinline__ float row16_sum(float x) {  // verified r1-r8
  x += dpp_mov<0xB1>(x);
  x += dpp_mov<0x4E>(x);
  x += dpp_mov<0x141>(x);
  x += dpp_mov<0x140>(x);
  return x;
}
__device__ __forceinline__ float full64_sum(float x) {
  x = row16_sum(x);
  x += __shfl_xor(x, 16, 64);
  x += __shfl_xor(x, 32, 64);
  return x;
}
__device__ __forceinline__ float full64_max(float x) {
  x = fmaxf(x, dpp_mov<0xB1>(x));
  x = fmaxf(x, dpp_mov<0x4E>(x));
  x = fmaxf(x, dpp_mov<0x141>(x));
  x = fmaxf(x, dpp_mov<0x140>(x));
  x = fmaxf(x, __shfl_xor(x, 16, 64));
  x = fmaxf(x, __shfl_xor(x, 32, 64));
  return x;
}

// ---- prep A: pack W into bf16 fragments (hi only). 32 blocks. -------------
__global__ void prep_kernel(const float* __restrict__ Wt,
                            const float* __restrict__ Wht,
                            const float* __restrict__ Wrel,
                            unsigned char* __restrict__ ws) {
  int slot = blockIdx.x * 256 + threadIdx.x;      // 8192 slots
  const float* W;
  unsigned char* base;
  if (slot < 2048)      { W = Wt;   base = ws + WT_OFF; }
  else if (slot < 6144) { W = Wht;  base = ws + WHT_OFF;  slot -= 2048; }
  else                  { W = Wrel; base = ws + WREL_OFF; slot -= 6144; }
  int lane = slot & 63, pair = slot >> 6;
  int n  = (pair & 7) * 16 + (lane & 15);
  int k0 = (pair >> 3) * 32 + (lane >> 4) * 8;
  short8 hv;
  #pragma unroll
  for (int j = 0; j < 8; ++j)
    hv[j] = (short)f2bf(W[(size_t)(k0 + j) * UU + n]);
  *reinterpret_cast<short8*>(base + (size_t)pair * 1024 + lane * 16) = hv;
}

// ---- prep B: te table + R table over the whole vocab ----------------------
// te[v] = tanh(emb[v]@W_trans + b_trans)  (bf16)
// R[v]  = te[v]@W_rel + b_rel             (f32, bias folded — R8-verified)
// Only 30MB of writes (vs R8's 70MB) — the cheap hoist.
__launch_bounds__(1024, 4)
__global__ void prep_teR(const float* __restrict__ emb_f32,
                         const float* __restrict__ b_trans,
                         const float* __restrict__ b_rel,
                         const unsigned char* __restrict__ wsr,
                         unsigned short* __restrict__ te_g,
                         float* __restrict__ R_g) {
  __shared__ unsigned short TEB[192 * 128];
  const int tid  = threadIdx.x;
  const int base = blockIdx.x * 192;
  const int w    = tid >> 6;
  const int lane = tid & 63;
  const int li   = lane & 15;
  const int lg   = lane >> 4;
  const int nt   = w & 7;
  const int rh   = w >> 3;

  // stage 192 consecutive emb rows (f32 -> bf16, swizzled) — coalesced
  float4 xv[3], yv[3];
  #pragma unroll
  for (int j = 0; j < 3; ++j) {
    int o = tid + j * 1024, row = o >> 4, pc = o & 15;
    int grow = base + row; if (grow > NV - 1) grow = NV - 1;
    int clog = pc ^ (row & 15);
    const float* fb = emb_f32 + (size_t)grow * UU + clog * 8;
    xv[j] = *reinterpret_cast<const float4*>(fb);
    yv[j] = *reinterpret_cast<const float4*>(fb + 4);
  }
  const unsigned char* wtb  = wsr + WT_OFF;
  const unsigned char* wrlb = wsr + WREL_OFF;
  short8 B1h[4];
  #pragma unroll
  for (int kt = 0; kt < 4; ++kt)
    B1h[kt] = *reinterpret_cast<const short8*>(
        wtb + (size_t)(kt * 8 + nt) * 1024 + lane * 16);
  #pragma unroll
  for (int j = 0; j < 3; ++j) {
    int o = tid + j * 1024;
    uint4 pk = { cvtpk(xv[j].x, xv[j].y), cvtpk(xv[j].z, xv[j].w),
                 cvtpk(yv[j].x, yv[j].y), cvtpk(yv[j].z, yv[j].w) };
    *reinterpret_cast<uint4*>(&TEB[o * 8]) = pk;
  }
  const float4 btr4 = *reinterpret_cast<const float4*>(b_trans + nt * 16 + lg * 4);
  __syncthreads();

  // GEMM1: 6 row-tiles x 4 kt per wave (verbatim, verified r0-r8)
  f32x4 acc[6];
  #pragma unroll
  for (int q = 0; q < 6; ++q) acc[q] = f32x4{0.f, 0.f, 0.f, 0.f};
  #pragma unroll
  for (int kt = 0; kt < 4; ++kt) {
    #pragma unroll
    for (int q = 0; q < 6; ++q) {
      const short8 b = *reinterpret_cast<const short8*>(
          &TEB[((rh * 6 + q) * 16 + li) * 128 + (((kt * 4 + lg) ^ li) << 3)]);
      acc[q] = __builtin_amdgcn_mfma_f32_16x16x32_bf16(B1h[kt], b, acc[q], 0, 0, 0);
    }
  }
  __syncthreads();  // all emb reads done before te overwrite

  // epilogue: te -> TEB (swizzled) AND te_g (global) — R8-verified
  const int cc8 = nt * 2 + (lg >> 1);
  const int hb8 = (lg & 1) << 3;
  #pragma unroll
  for (int q = 0; q < 6; ++q) {
    int row  = (rh * 6 + q) * 16 + li;
    int grow = base + row; if (grow > NV - 1) grow = NV - 1;  // dup write, same value
    float v0 = ftanh(acc[q][0] + btr4.x);
    float v1 = ftanh(acc[q][1] + btr4.y);
    float v2 = ftanh(acc[q][2] + btr4.z);
    float v3 = ftanh(acc[q][3] + btr4.w);
    uint2 pk = { cvtpk(v0, v1), cvtpk(v2, v3) };
    *reinterpret_cast<uint2*>(
        reinterpret_cast<char*>(TEB) + row * 256 + (((cc8 ^ li) << 4) | hb8)) = pk;
    *reinterpret_cast<uint2*>(te_g + (size_t)grow * UU + nt * 16 + lg * 4) = pk;
  }
  __syncthreads();  // te in TEB ready

  // R pass: R = te @ W_rel + b_rel (R8 pass==2, verbatim)
  const float4 brl4 = *reinterpret_cast<const float4*>(b_rel + nt * 16 + lg * 4);
  f32x4 a2[6];
  #pragma unroll
  for (int q = 0; q < 6; ++q) a2[q] = f32x4{0.f, 0.f, 0.f, 0.f};
  #pragma unroll
  for (int kt = 0; kt < 4; ++kt) {
    const short8 Wf = *reinterpret_cast<const short8*>(
        wrlb + (size_t)(kt * 8 + nt) * 1024 + lane * 16);
    #pragma unroll
    for (int q = 0; q < 6; ++q) {
      const short8 b = *reinterpret_cast<const short8*>(
          &TEB[((rh * 6 + q) * 16 + li) * 128 + (((kt * 4 + lg) ^ li) << 3)]);
      a2[q] = __builtin_amdgcn_mfma_f32_16x16x32_bf16(Wf, b, a2[q], 0, 0, 0);
    }
  }
  #pragma unroll
  for (int q = 0; q < 6; ++q) {
    int row  = (rh * 6 + q) * 16 + li;
    int grow = base + row; if (grow > NV - 1) grow = NV - 1;
    float4 v = { a2[q][0] + brl4.x, a2[q][1] + brl4.y,
                 a2[q][2] + brl4.z, a2[q][3] + brl4.w };
    *reinterpret_cast<float4*>(R_g + (size_t)grow * UU + nt * 16 + lg * 4) = v;
  }
}

// ---- fused per-(b,t) kernel: 1024 blocks x 1024 threads (16 waves) ---------
// Stages only 128 head/tail te rows (head l -> TEB row l, tail l -> 64+l);
// relation comes from the precomputed R table (coalesced f32 gathers issued
// at entry, latency hidden under staging+GEMM).  ht GEMM (accH) = R7
// verbatim with row remap.  Barriers: 3.
__launch_bounds__(1024, 8)
__global__ void fused_bt(const int* __restrict__ triples,
                         const unsigned short* __restrict__ te_g,
                         const float* __restrict__ R_g,
                         const float* __restrict__ b_ht,
                         const int* __restrict__ sent_triples,
                         const unsigned char* __restrict__ wsr,
                         float* __restrict__ out) {
  __shared__ unsigned short TEB[128 * 128];    // 32KB: head|tail te rows
  __shared__ float EWt[8][64];
  __shared__ float PART[8][256];
  __shared__ int MATCH[512];
  __shared__ int NM;

  const int tid  = threadIdx.x;
  const int bt   = blockIdx.x;
  const int w    = tid >> 6;
  const int lane = tid & 63;
  const int li   = lane & 15;
  const int lg   = lane >> 4;
  const int nt   = w & 7;
  const int rh   = w >> 3;
  const int mh   = rh * 2;
  const int* tb  = triples + (size_t)bt * 192;

  // staging tokens: slot o covers row o>>4; head rows 0..63 use tb[3l],
  // tail rows 64..127 use tb[3l+2].  16 adjacent tids share a row (broadcast).
  int stok[2];
  #pragma unroll
  for (int j = 0; j < 2; ++j) {
    int row = (tid + j * 1024) >> 4;
    stok[j] = tb[3 * (row & 63) + ((row >> 6) << 1)];
  }
  // relation tokens for this thread's 8 e_weight slots: l=(mh+mi)*16+lg*4+r
  // (16 lanes with same lg share them -> broadcast loads)
  int rtok[2][4];
  #pragma unroll
  for (int mi = 0; mi < 2; ++mi)
    #pragma unroll
    for (int r = 0; r < 4; ++r)
      rtok[mi][r] = tb[3 * ((mh + mi) * 16 + lg * 4 + r) + 1];

  int sidx = -1;
  if (tid < SS) sidx = sent_triples[(size_t)(bt >> 6) * SS + tid];
  if (tid == 0) NM = 0;

  // ---- stage 128 te rows (bf16, swizzled source chunk) -------------------
  short8 sv[2];
  #pragma unroll
  for (int j = 0; j < 2; ++j) {
    int o = tid + j * 1024, row = o >> 4, pc = o & 15;
    int clog = pc ^ (row & 15);
    sv[j] = *reinterpret_cast<const short8*>(
        te_g + (size_t)stok[j] * UU + clog * 8);
  }
  // ---- R gathers: R[rtok][u = nt*16+li] — 16 lanes read 64B contiguous ---
  float Rv[2][4];
  #pragma unroll
  for (int mi = 0; mi < 2; ++mi)
    #pragma unroll
    for (int r = 0; r < 4; ++r)
      Rv[mi][r] = R_g[(size_t)rtok[mi][r] * UU + nt * 16 + li];

  #pragma unroll
  for (int j = 0; j < 2; ++j)
    *reinterpret_cast<short8*>(&TEB[(tid + j * 1024) * 8]) = sv[j];

  const unsigned char* whtb = wsr + WHT_OFF;
  const float bhv = b_ht[nt * 16 + li];
  // prefetch first W-frag before the barrier
  short8 Wc = *reinterpret_cast<const short8*>(
      whtb + (size_t)nt * 1024 + lane * 16);
  __syncthreads();  // (b1) staging complete; NM=0 visible

  // match-find: overlaps GEMM (MATCH/NM not read until scatter)
  if (sidx == (bt & 63))
    MATCH[atomicAdd(&NM, 1)] = tid;

  // ============ ht GEMM: K=256 (head chunks kt<4, tail chunks kt>=4) =====
  f32x4 accH[2] = {{0.f,0.f,0.f,0.f},{0.f,0.f,0.f,0.f}};
  #pragma unroll
  for (int kt = 0; kt < 8; ++kt) {
    short8 Wn;
    if (kt < 7)
      Wn = *reinterpret_cast<const short8*>(
          whtb + (size_t)((kt + 1) * 8 + nt) * 1024 + lane * 16);
    const int hb  = (kt < 4) ? 0 : 64;
    const int c16 = (kt & 3) * 4 + lg;
    #pragma unroll
    for (int mi = 0; mi < 2; ++mi) {
      const int row = hb + (mh + mi) * 16 + li;    // row & 15 == li
      const short8 a = *reinterpret_cast<const short8*>(
          &TEB[row * 128 + ((c16 ^ li) << 3)]);
      accH[mi] = __builtin_amdgcn_mfma_f32_16x16x32_bf16(a, Wc, accH[mi], 0, 0, 0);
    }
    if (kt < 7) Wc = Wn;
  }

  // e_weight partials: l = (mh+mi)*16 + lg*4 + r; rel from R table
  #pragma unroll
  for (int mi = 0; mi < 2; ++mi) {
    #pragma unroll
    for (int r = 0; r < 4; ++r) {
      float p = ftanh(accH[mi][r] + bhv) * Rv[mi][r];
      p = row16_sum(p);
      if (li == 0) EWt[nt][(mh + mi) * 16 + lg * 4 + r] = p;
    }
  }
  __syncthreads();  // (b2) EWt ready

  // redundant per-wave softmax (verified r5-r8)
  float alpha;
  {
    float e = 0.f;
    #pragma unroll
    for (int n = 0; n < 8; ++n) e += EWt[n][lane];
    float mx = full64_max(e);
    float ex = __expf(e - mx);
    float sm = full64_sum(ex);
    alpha = ex / sm;
  }

  // weighted sum: paired-bf16 b32 reads, 8 l's per thread
  {
    int cp  = tid & 127, lgp = w >> 1;    // wave-uniform l-group
    int c0  = cp << 1;
    int k   = c0 >> 7;                    // 0: head rows 0..63, 1: tail 64..127
    int cc  = c0 & 127;
    int w8  = cc >> 3, bofs = (cc & 7) << 1;
    float o0 = 0.f, o1 = 0.f;
    #pragma unroll
    for (int j = 0; j < 8; ++j) {
      int lr  = lgp * 8 + j;
      float al = __int_as_float(
          __builtin_amdgcn_readlane(__float_as_int(alpha), lr));
      int row = (k << 6) + lr;
      unsigned u = *reinterpret_cast<const unsigned*>(
          reinterpret_cast<const char*>(TEB) + row * 256 +
          (((w8 ^ (row & 15)) << 4) | bofs));
      o0 = fmaf(al, __uint_as_float(u << 16), o0);
      o1 = fmaf(al, __uint_as_float(u & 0xFFFF0000u), o1);
    }
    *reinterpret_cast<float2*>(&PART[lgp][c0]) = make_float2(o0, o1);
  }
  __syncthreads();  // (b3) PART + MATCH/NM ready

  // scatter: participating waves fold the 8-way reduce (verified r5-r8)
  {
    const int b  = bt >> 6;
    const int nm = NM;
    if (w < nm) {
      float4 v = {0.f, 0.f, 0.f, 0.f};
      #pragma unroll
      for (int g = 0; g < 8; ++g) {
        float4 pp = reinterpret_cast<const float4*>(&PART[g][0])[lane];
        v.x += pp.x; v.y += pp.y; v.z += pp.z; v.w += pp.w;
      }
      for (int q = w; q < nm; q += 16) {
        int s = MATCH[q];
        reinterpret_cast<float4*>(out + ((size_t)(b * SS + s)) * 256)[lane] = v;
      }
    }
  }
}

extern "C" void kernel_launch(void* const* d_in, const int* in_sizes, int n_in,
                              void* d_out, int out_size, void* d_ws, size_t ws_size,
                              hipStream_t stream) {
  const int*   triples      = (const int*)d_in[1];
  const int*   sent_triples = (const int*)d_in[2];
  const float* emb_table    = (const float*)d_in[3];
  const float* W_trans      = (const float*)d_in[4];
  const float* b_trans      = (const float*)d_in[5];
  const float* W_ht         = (const float*)d_in[6];
  const float* b_ht         = (const float*)d_in[7];
  const float* W_rel        = (const float*)d_in[8];
  const float* b_rel        = (const float*)d_in[9];
  float* out = (float*)d_out;
  unsigned char* ws = (unsigned char*)d_ws;
  unsigned short* te_g = (unsigned short*)(ws + TE_OFF);
  float* R_g = (float*)(ws + R_OFF);

  prep_kernel<<<32, 256, 0, stream>>>(W_trans, W_ht, W_rel, ws);
  prep_teR<<<(NV + 191) / 192, 1024, 0, stream>>>(
      emb_table, b_trans, b_rel, ws, te_g, R_g);
  fused_bt<<<BB * TT, 1024, 0, stream>>>(
      triples, te_g, R_g, b_ht, sent_triples, ws, out);
}

// Round 10
// 40.297 us; speedup vs baseline: 1.3334x; 1.1788x over previous
//
#include <hip/hip_runtime.h>
#include <cstdint>
#include <cstddef>

typedef short short8 __attribute__((ext_vector_type(8)));
typedef float f32x4 __attribute__((ext_vector_type(4)));

#define BB 16
#define SS 512
#define TT 64
#define LL 64
#define UU 128
#define NV 40000

// ws layout (bytes) — WT region retired (W_trans frags built in-register)
#define WHT_OFF   0u                        // W_ht frags: 64 x 1KB = 64KB
#define WREL_OFF  (WHT_OFF + 65536u)        // W_rel frags: 32 x 1KB = 32KB
#define TE_OFF    (WREL_OFF + 32768u)       // te table bf16: 10.24MB

__device__ __forceinline__ unsigned short f2bf(float x) {  // rtne f32->bf16
  unsigned u = __float_as_uint(x);
  unsigned r = ((u >> 16) & 1u) + 0x7FFFu;
  return (unsigned short)((u + r) >> 16);
}
__device__ __forceinline__ float ftanh(float x) {  // 1 - 2/(e^2x+1)
  float e = __expf(2.0f * x);
  return 1.0f - __fdividef(2.0f, e + 1.0f);
}
__device__ __forceinline__ unsigned cvtpk(float a, float b) {
  unsigned r;
  asm("v_cvt_pk_bf16_f32 %0, %1, %2" : "=v"(r) : "v"(a), "v"(b));
  return r;
}
template<int CTRL>
__device__ __forceinline__ float dpp_mov(float x) {
  return __int_as_float(__builtin_amdgcn_update_dpp(
      0, __float_as_int(x), CTRL, 0xF, 0xF, true));
}
__device__ __forceinline__ float row16_sum(float x) {  // verified r1-r9
  x += dpp_mov<0xB1>(x);
  x += dpp_mov<0x4E>(x);
  x += dpp_mov<0x141>(x);
  x += dpp_mov<0x140>(x);
  return x;
}
__device__ __forceinline__ float full64_sum(float x) {
  x = row16_sum(x);
  x += __shfl_xor(x, 16, 64);
  x += __shfl_xor(x, 32, 64);
  return x;
}
__device__ __forceinline__ float full64_max(float x) {
  x = fmaxf(x, dpp_mov<0xB1>(x));
  x = fmaxf(x, dpp_mov<0x4E>(x));
  x = fmaxf(x, dpp_mov<0x141>(x));
  x = fmaxf(x, dpp_mov<0x140>(x));
  x = fmaxf(x, __shfl_xor(x, 16, 64));
  x = fmaxf(x, __shfl_xor(x, 32, 64));
  return x;
}

// ---- prep_te: te table over the whole vocab + WHT/WREL frag packing -------
// te[v] = tanh(emb[v]@W_trans + b_trans)  (bf16).  417 blocks x 512 threads
// (8 waves), 96 consecutive vocab rows each — >1.6 blocks/CU for latency
// overlap (R7's 209x1024 left 47 CUs idle at 1 block/CU).
// W_trans frags are built per-wave from global f32 (f2bf — bit-identical to
// the retired prep_kernel packing).  Blocks 0..11 additionally pack the
// WHT/WREL fragments for fused (verbatim prep_kernel slot math, 512 slots ea).
__launch_bounds__(512, 8)
__global__ void prep_te(const float* __restrict__ emb_f32,
                        const float* __restrict__ Wt,
                        const float* __restrict__ Wht,
                        const float* __restrict__ Wrel,
                        const float* __restrict__ b_trans,
                        unsigned char* __restrict__ ws,
                        unsigned short* __restrict__ te_g) {
  __shared__ unsigned short TEB[96 * 128];   // 24KB
  const int tid  = threadIdx.x;
  const int base = blockIdx.x * 96;
  const int w    = tid >> 6;      // wave 0..7
  const int lane = tid & 63;
  const int li   = lane & 15;
  const int lg   = lane >> 4;
  const int nt   = w;             // wave owns n-tile w, all 6 row-tiles

  // stage 96 consecutive emb rows (f32 -> bf16, swizzled source chunk)
  float4 xv[3], yv[3];
  #pragma unroll
  for (int j = 0; j < 3; ++j) {
    int o = tid + j * 512, row = o >> 4, pc = o & 15;
    int grow = base + row; if (grow > NV - 1) grow = NV - 1;
    int clog = pc ^ (row & 15);
    const float* fb = emb_f32 + (size_t)grow * UU + clog * 8;
    xv[j] = *reinterpret_cast<const float4*>(fb);
    yv[j] = *reinterpret_cast<const float4*>(fb + 4);
  }
  // W_trans frags direct from global: B1h[kt][j] = bf16(Wt[(kt*32+lg*8+j)*128
  // + nt*16+li]) — identical values to the old packed path.
  short8 B1h[4];
  #pragma unroll
  for (int kt = 0; kt < 4; ++kt) {
    #pragma unroll
    for (int j = 0; j < 8; ++j)
      B1h[kt][j] = (short)f2bf(Wt[(size_t)(kt * 32 + lg * 8 + j) * UU + nt * 16 + li]);
  }
  #pragma unroll
  for (int j = 0; j < 3; ++j) {
    int o = tid + j * 512;
    uint4 pk = { cvtpk(xv[j].x, xv[j].y), cvtpk(xv[j].z, xv[j].w),
                 cvtpk(yv[j].x, yv[j].y), cvtpk(yv[j].z, yv[j].w) };
    *reinterpret_cast<uint4*>(&TEB[o * 8]) = pk;
  }
  const float4 btr4 = *reinterpret_cast<const float4*>(b_trans + nt * 16 + lg * 4);
  __syncthreads();

  // GEMM1: 6 row-tiles x 4 kt per wave (verified swizzle: row&15 == li)
  f32x4 acc[6];
  #pragma unroll
  for (int q = 0; q < 6; ++q) acc[q] = f32x4{0.f, 0.f, 0.f, 0.f};
  #pragma unroll
  for (int kt = 0; kt < 4; ++kt) {
    #pragma unroll
    for (int q = 0; q < 6; ++q) {
      const short8 b = *reinterpret_cast<const short8*>(
          &TEB[(q * 16 + li) * 128 + (((kt * 4 + lg) ^ li) << 3)]);
      acc[q] = __builtin_amdgcn_mfma_f32_16x16x32_bf16(B1h[kt], b, acc[q], 0, 0, 0);
    }
  }

  // epilogue: tanh + bias -> global te table (bf16 pairs), R7-verified math
  #pragma unroll
  for (int q = 0; q < 6; ++q) {
    int row  = q * 16 + li;
    int grow = base + row; if (grow > NV - 1) grow = NV - 1;  // dup write, same value
    float v0 = ftanh(acc[q][0] + btr4.x);
    float v1 = ftanh(acc[q][1] + btr4.y);
    float v2 = ftanh(acc[q][2] + btr4.z);
    float v3 = ftanh(acc[q][3] + btr4.w);
    uint2 pk = { cvtpk(v0, v1), cvtpk(v2, v3) };
    *reinterpret_cast<uint2*>(te_g + (size_t)grow * UU + nt * 16 + lg * 4) = pk;
  }

  // blocks 0..11: pack WHT (4096 slots) + WREL (2048 slots) for fused
  if (blockIdx.x < 12) {
    int slot = blockIdx.x * 512 + tid;          // 0..6143
    const float* W;
    unsigned char* fb;
    if (slot < 4096) { W = Wht;  fb = ws + WHT_OFF; }
    else             { W = Wrel; fb = ws + WREL_OFF; slot -= 4096; }
    int ln = slot & 63, pair = slot >> 6;
    int n  = (pair & 7) * 16 + (ln & 15);
    int k0 = (pair >> 3) * 32 + (ln >> 4) * 8;
    short8 hv;
    #pragma unroll
    for (int j = 0; j < 8; ++j)
      hv[j] = (short)f2bf(W[(size_t)(k0 + j) * UU + n]);
    *reinterpret_cast<short8*>(fb + (size_t)pair * 1024 + ln * 16) = hv;
  }
}

// ---- fused per-(b,t) kernel: R7 VERBATIM (verified 43.4us total) ----------
// Gathers pre-transformed te rows (bf16) into TEB, GEMM2, softmax, wsum,
// scatter.  Barriers: 3.  TEB swizzle: logical 16B-chunk c16 of row r at
// physical chunk c16^(r&15).
__launch_bounds__(1024, 8)
__global__ void fused_bt(const int* __restrict__ triples,
                         const unsigned short* __restrict__ te_g,
                         const float* __restrict__ b_ht,
                         const float* __restrict__ b_rel,
                         const int* __restrict__ sent_triples,
                         const unsigned char* __restrict__ wsr,
                         float* __restrict__ out) {
  __shared__ unsigned short TEB[192 * 128];    // 48KB: te rows (bf16)
  __shared__ float EWt[8][64];                 // e_weight partials
  __shared__ float PART[8][256];               // wsum partials (8 l-groups)
  __shared__ int MATCH[512];
  __shared__ int NM;

  const int tid  = threadIdx.x;
  const int bt   = blockIdx.x;
  const int w    = tid >> 6;
  const int lane = tid & 63;
  const int li   = lane & 15;
  const int lg   = lane >> 4;
  const int nt   = w & 7;
  const int rh   = w >> 3;

  // tokens per-thread direct (R6-verified broadcast-coalesced pattern)
  int tok[3];
  #pragma unroll
  for (int j = 0; j < 3; ++j) {
    int row = (tid + j * 1024) >> 4;
    tok[j] = triples[(size_t)bt * 192 + row];
  }
  int sidx = -1;
  if (tid < SS) sidx = sent_triples[(size_t)(bt >> 6) * SS + tid];
  if (tid == 0) NM = 0;

  // ---- stage 192 te rows (bf16, 16B/slot) --------------------------------
  short8 sv[3];
  #pragma unroll
  for (int j = 0; j < 3; ++j) {
    int o = tid + j * 1024, row = o >> 4, pc = o & 15;
    int clog = pc ^ (row & 15);
    sv[j] = *reinterpret_cast<const short8*>(
        te_g + (size_t)tok[j] * UU + clog * 8);
  }
  #pragma unroll
  for (int j = 0; j < 3; ++j)
    *reinterpret_cast<short8*>(&TEB[(tid + j * 1024) * 8]) = sv[j];

  const unsigned char* whtb = wsr + WHT_OFF;
  const unsigned char* wrlb = wsr + WREL_OFF;
  const float bhv  = b_ht[nt * 16 + li];
  const float brlv = b_rel[nt * 16 + li];
  // prefetch GEMM2 first W-frag before the barrier
  short8 Wc = *reinterpret_cast<const short8*>(
      whtb + (size_t)nt * 1024 + lane * 16);
  __syncthreads();  // (b1) staging complete; NM=0 visible

  // ---- match-find: overlaps GEMM2 (MATCH/NM not read until scatter) ------
  if (sidx == (bt & 63))
    MATCH[atomicAdd(&NM, 1)] = tid;

  // ============ GEMM2: ht_t / rel_t / e_weight (2 m-tiles per wave) =======
  // head = te row 3l+0, rel = 3l+1, tail = 3l+2  (l = m*16 + li)
  const int mh = rh * 2;
  f32x4 accH[2] = {{0.f,0.f,0.f,0.f},{0.f,0.f,0.f,0.f}};
  f32x4 accR[2] = {{0.f,0.f,0.f,0.f},{0.f,0.f,0.f,0.f}};

  #pragma unroll
  for (int kt = 0; kt < 8; ++kt) {   // head_tail: K=256
    short8 Wn;
    if (kt < 7)
      Wn = *reinterpret_cast<const short8*>(
          whtb + (size_t)((kt + 1) * 8 + nt) * 1024 + lane * 16);
    else
      Wn = *reinterpret_cast<const short8*>(
          wrlb + (size_t)nt * 1024 + lane * 16);
    const int koff = (kt < 4) ? 0 : 2;
    const int c16  = (kt & 3) * 4 + lg;
    #pragma unroll
    for (int mi = 0; mi < 2; ++mi) {
      const int row = 48 * (mh + mi) + 3 * li + koff;
      const short8 a = *reinterpret_cast<const short8*>(
          &TEB[row * 128 + ((c16 ^ (row & 15)) << 3)]);
      accH[mi] = __builtin_amdgcn_mfma_f32_16x16x32_bf16(a, Wc, accH[mi], 0, 0, 0);
    }
    Wc = Wn;
  }
  #pragma unroll
  for (int kt = 0; kt < 4; ++kt) {   // relation: K=128, rows 3l+1
    short8 Wn;
    if (kt < 3)
      Wn = *reinterpret_cast<const short8*>(
          wrlb + (size_t)((kt + 1) * 8 + nt) * 1024 + lane * 16);
    const int c16 = kt * 4 + lg;
    #pragma unroll
    for (int mi = 0; mi < 2; ++mi) {
      const int row = 48 * (mh + mi) + 3 * li + 1;
      const short8 a = *reinterpret_cast<const short8*>(
          &TEB[row * 128 + ((c16 ^ (row & 15)) << 3)]);
      accR[mi] = __builtin_amdgcn_mfma_f32_16x16x32_bf16(a, Wc, accR[mi], 0, 0, 0);
    }
    Wc = Wn;
  }

  // e_weight partials: l = (mh+mi)*16 + lg*4 + r; DPP-reduce over 16 u lanes
  #pragma unroll
  for (int mi = 0; mi < 2; ++mi) {
    #pragma unroll
    for (int r = 0; r < 4; ++r) {
      float p = ftanh(accH[mi][r] + bhv) * (accR[mi][r] + brlv);
      p = row16_sum(p);
      if (li == 0) EWt[nt][(mh + mi) * 16 + lg * 4 + r] = p;
    }
  }
  __syncthreads();  // (b2) EWt ready

  // ============ redundant softmax (every wave; no barrier after) ==========
  float alpha;
  {
    float e = 0.f;
    #pragma unroll
    for (int n = 0; n < 8; ++n) e += EWt[n][lane];
    float mx = full64_max(e);
    float ex = __expf(e - mx);
    float sm = full64_sum(ex);
    alpha = ex / sm;
  }

  // ============ weighted sum: paired-bf16 b32 reads, 8 l's per thread ======
  {
    int cp  = tid & 127, lgp = w >> 1;
    int c0  = cp << 1;
    int k   = (c0 >> 7) << 1;              // head rows 3l, tail rows 3l+2
    int cc  = c0 & 127;
    int w8  = cc >> 3, bofs = (cc & 7) << 1;
    float o0 = 0.f, o1 = 0.f;
    #pragma unroll
    for (int j = 0; j < 8; ++j) {
      int l = lgp * 8 + j;
      float al = __int_as_float(
          __builtin_amdgcn_readlane(__float_as_int(alpha), l));
      int row = 3 * l + k;
      unsigned u = *reinterpret_cast<const unsigned*>(
          reinterpret_cast<const char*>(TEB) + row * 256 +
          (((w8 ^ (row & 15)) << 4) | bofs));
      o0 = fmaf(al, __uint_as_float(u << 16), o0);
      o1 = fmaf(al, __uint_as_float(u & 0xFFFF0000u), o1);
    }
    *reinterpret_cast<float2*>(&PART[lgp][c0]) = make_float2(o0, o1);
  }
  __syncthreads();  // (b3) PART ready; MATCH/NM final

  // ============ scatter: participating waves fold the 8-way reduce ========
  {
    const int b  = bt >> 6;
    const int nm = NM;
    if (w < nm) {
      float4 v = {0.f, 0.f, 0.f, 0.f};
      #pragma unroll
      for (int g = 0; g < 8; ++g) {
        float4 p = reinterpret_cast<const float4*>(&PART[g][0])[lane];
        v.x += p.x; v.y += p.y; v.z += p.z; v.w += p.w;
      }
      for (int q = w; q < nm; q += 16) {
        int s = MATCH[q];
        reinterpret_cast<float4*>(out + ((size_t)(b * SS + s)) * 256)[lane] = v;
      }
    }
  }
}

extern "C" void kernel_launch(void* const* d_in, const int* in_sizes, int n_in,
                              void* d_out, int out_size, void* d_ws, size_t ws_size,
                              hipStream_t stream) {
  const int*   triples      = (const int*)d_in[1];
  const int*   sent_triples = (const int*)d_in[2];
  const float* emb_table    = (const float*)d_in[3];
  const float* W_trans      = (const float*)d_in[4];
  const float* b_trans      = (const float*)d_in[5];
  const float* W_ht         = (const float*)d_in[6];
  const float* b_ht         = (const float*)d_in[7];
  const float* W_rel        = (const float*)d_in[8];
  const float* b_rel        = (const float*)d_in[9];
  float* out = (float*)d_out;
  unsigned char* ws = (unsigned char*)d_ws;
  unsigned short* te_g = (unsigned short*)(ws + TE_OFF);

  prep_te<<<(NV + 95) / 96, 512, 0, stream>>>(
      emb_table, W_trans, W_ht, W_rel, b_trans, ws, te_g);
  fused_bt<<<BB * TT, 1024, 0, stream>>>(
      triples, te_g, b_ht, b_rel, sent_triples, ws, out);
}